// Round 11
// baseline (211.955 us; speedup 1.0000x reference)
//
#include <hip/hip_runtime.h>
#include <math.h>

#define D_MODEL 512
#define SEQ     4096
#define BATCH   4
#define BS      (BATCH * SEQ)  // 16384

// Diagnostic: attn_tile repeats its idempotent body 4x so it ranks above
// the ~44us harness fills and exposes its counters. True cost = row/4.
#define REPS_ATTN 4

typedef __attribute__((ext_vector_type(8))) short  short8;   // 8 x bf16 (4 VGPRs)
typedef __attribute__((ext_vector_type(4))) float  float4v;  // MFMA C/D

#define GAS __attribute__((address_space(1)))
#define LAS __attribute__((address_space(3)))

__device__ __forceinline__ void gld_lds16(const void* g, void* l) {
  __builtin_amdgcn_global_load_lds((const GAS unsigned int*)g,
                                   (LAS unsigned int*)l, 16, 0, 0);
}

__device__ __forceinline__ unsigned short bf16r(float f) {
  unsigned int u = __builtin_bit_cast(unsigned int, f);
  u += 0x7fffu + ((u >> 16) & 1u);  // RTNE
  return (unsigned short)(u >> 16);
}

__device__ __forceinline__ uint4 pack8(float4 a, float4 b) {
  uint4 o;
  o.x = bf16r(a.x) | ((unsigned)bf16r(a.y) << 16);
  o.y = bf16r(a.z) | ((unsigned)bf16r(a.w) << 16);
  o.z = bf16r(b.x) | ((unsigned)bf16r(b.y) << 16);
  o.w = bf16r(b.z) | ((unsigned)bf16r(b.w) << 16);
  return o;
}

// --------------------------------------------------------------------------
// Weight prep only (x conversion fused into qv_gemm):
//   blocks 0..63  : W_qk [k][n] -> Wqkt [n][k] bf16 (tile transpose)
//   blocks 64..191: W_v straight convert to bf16
// --------------------------------------------------------------------------
__global__ __launch_bounds__(256) void cvt_w(const float* __restrict__ Wqk,
                                             unsigned short* __restrict__ Wqkt,
                                             const float* __restrict__ Wv,
                                             unsigned short* __restrict__ Wvb) {
  if (blockIdx.x < 64) {
    __shared__ float tile[64][65];
    const int bx = blockIdx.x & 7;   // n-tile
    const int by = blockIdx.x >> 3;  // k-tile
    const int tx = threadIdx.x & 63;
    const int ty = threadIdx.x >> 6;
    for (int r = ty; r < 64; r += 4)
      tile[r][tx] = Wqk[(size_t)(by * 64 + r) * D_MODEL + bx * 64 + tx];
    __syncthreads();
    for (int r = ty; r < 64; r += 4)
      Wqkt[(size_t)(bx * 64 + r) * D_MODEL + by * 64 + tx] = bf16r(tile[tx][r]);
  } else {
    const int idx = ((blockIdx.x - 64) * 256 + threadIdx.x) * 8;
    const float4 a = *(const float4*)(Wv + idx);
    const float4 b = *(const float4*)(Wv + idx + 4);
    *(uint4*)(Wvb + idx) = pack8(a, b);
  }
}

// --------------------------------------------------------------------------
// Fused convert + Q-GEMM + Vt-GEMM (round-10 version, unchanged).
// --------------------------------------------------------------------------
template <bool QP>
__device__ __forceinline__ void gemm_path(const float* __restrict__ x,
                                          const unsigned short* __restrict__ Wgt,
                                          const float* __restrict__ bias,
                                          unsigned short* __restrict__ xb,
                                          unsigned short* __restrict__ C,
                                          int a0, float scale,
                                          unsigned short* smem) {
  unsigned short* Ws = smem;          // 32768 shorts (64 KB)
  unsigned short* As = smem + 32768;  // 4096 shorts (8 KB)

  const int t    = threadIdx.x;
  const int w    = t >> 6;
  const int lane = t & 63;
  const int q    = lane >> 4;
  const int c    = lane & 15;
  const int wbase = w * 128;
  const int sw   = c & 7;

  const int arow = t >> 2;        // 0..63
  const int acb  = (t & 3) * 16;  // 0,16,32,48

  constexpr int NI = QP ? 8 : 4;
  constexpr int NJ = QP ? 4 : 8;

  float4v acc[NI][NJ];
#pragma unroll
  for (int i = 0; i < NI; ++i)
#pragma unroll
    for (int j = 0; j < NJ; ++j) acc[i][j] = (float4v){0.f, 0.f, 0.f, 0.f};

  for (int k0 = 0; k0 < D_MODEL; k0 += 64) {
#pragma unroll
    for (int it = 0; it < 16; ++it) {
      const int idx = it * 256 + t;  // 0..4095
      const int r   = idx >> 3;
      const int s   = idx & 7;
      gld_lds16(Wgt + (size_t)r * D_MODEL + k0 + ((s ^ (r & 7)) << 3),
                &Ws[idx * 8]);
    }
    {
      const float* xg = x + (size_t)(a0 + arow) * D_MODEL + k0 + acb;
      const float4 f0 = *(const float4*)(xg + 0);
      const float4 f1 = *(const float4*)(xg + 4);
      const float4 f2 = *(const float4*)(xg + 8);
      const float4 f3 = *(const float4*)(xg + 12);
      const uint4 u0 = pack8(f0, f1);
      const uint4 u1 = pack8(f2, f3);
      const int s0 = (t & 3) * 2;
      const int rk = arow & 7;
      *(uint4*)&As[arow * 64 + ((s0 ^ rk) << 3)]       = u0;
      *(uint4*)&As[arow * 64 + (((s0 + 1) ^ rk) << 3)] = u1;
      if (QP) {
        unsigned short* xo = xb + (size_t)(a0 + arow) * D_MODEL + k0 + acb;
        *(uint4*)xo       = u0;
        *(uint4*)(xo + 8) = u1;
      }
    }
    __syncthreads();

#pragma unroll
    for (int kc = 0; kc < 2; ++kc) {
      const int slot = ((kc * 4 + q) ^ sw) * 8;
      short8 af[NI], bf[NJ];
#pragma unroll
      for (int i = 0; i < NI; ++i) {
        const unsigned short* src = QP ? &Ws[(wbase + i * 16 + c) * 64 + slot]
                                       : &As[(i * 16 + c) * 64 + slot];
        af[i] = *(const short8*)src;
      }
#pragma unroll
      for (int j = 0; j < NJ; ++j) {
        const unsigned short* src = QP ? &As[(j * 16 + c) * 64 + slot]
                                       : &Ws[(wbase + j * 16 + c) * 64 + slot];
        bf[j] = *(const short8*)src;
      }
#pragma unroll
      for (int i = 0; i < NI; ++i)
#pragma unroll
        for (int j = 0; j < NJ; ++j)
          acc[i][j] = __builtin_amdgcn_mfma_f32_16x16x32_bf16(af[i], bf[j], acc[i][j], 0, 0, 0);
    }
    __syncthreads();
  }

  if (QP) {
    constexpr int LD = 520;
#pragma unroll
    for (int j = 0; j < NJ; ++j) {
      const int row = j * 16 + c;
#pragma unroll
      for (int i = 0; i < NI; ++i) {
        uint2 pkt;
        pkt.x = (unsigned)bf16r(scale * acc[i][j][0]) |
                ((unsigned)bf16r(scale * acc[i][j][1]) << 16);
        pkt.y = (unsigned)bf16r(scale * acc[i][j][2]) |
                ((unsigned)bf16r(scale * acc[i][j][3]) << 16);
        *(uint2*)&smem[row * LD + wbase + i * 16 + 4 * q] = pkt;
      }
    }
    __syncthreads();
#pragma unroll
    for (int it = 0; it < 16; ++it) {
      const int idx = it * 256 + t;
      const int row = idx >> 6;
      const int ch  = idx & 63;
      *(uint4*)&C[(size_t)(a0 + row) * D_MODEL + ch * 8] =
          *(const uint4*)&smem[row * LD + ch * 8];
    }
  } else {
    constexpr int LD = 72;
#pragma unroll
    for (int j = 0; j < NJ; ++j) {
      const int dim = wbase + j * 16 + c;
      const float bvv = bias[dim];
#pragma unroll
      for (int i = 0; i < NI; ++i) {
        uint2 pkt;
        pkt.x = (unsigned)bf16r(acc[i][j][0] + bvv) |
                ((unsigned)bf16r(acc[i][j][1] + bvv) << 16);
        pkt.y = (unsigned)bf16r(acc[i][j][2] + bvv) |
                ((unsigned)bf16r(acc[i][j][3] + bvv) << 16);
        *(uint2*)&smem[dim * LD + i * 16 + 4 * q] = pkt;
      }
    }
    __syncthreads();
#pragma unroll
    for (int it = 0; it < 16; ++it) {
      const int idx = it * 256 + t;
      const int dim = idx >> 3;
      const int ch  = idx & 7;
      *(uint4*)&C[(size_t)dim * BS + a0 + ch * 8] =
          *(const uint4*)&smem[dim * LD + ch * 8];
    }
  }
}

__global__ __launch_bounds__(256, 2) void qv_gemm(const float* __restrict__ x,
                                                  const unsigned short* __restrict__ Wqkt,
                                                  const unsigned short* __restrict__ Wvb,
                                                  const float* __restrict__ bv,
                                                  unsigned short* __restrict__ xb,
                                                  unsigned short* __restrict__ Qb,
                                                  unsigned short* __restrict__ Vt,
                                                  float scale) {
  __shared__ unsigned short smem[36864];  // 72 KB union
  if (blockIdx.x < 256)
    gemm_path<true>(x, Wqkt, nullptr, xb, Qb, blockIdx.x * 64, scale, smem);
  else
    gemm_path<false>(x, Wvb, bv, nullptr, Vt, (blockIdx.x - 256) * 64, 1.0f, smem);
}

// --------------------------------------------------------------------------
// Windowed causal ALiBi attention, REPS_ATTN x (diagnostic). Block = 128
// threads (2 waves) = one 16-query tile; grid = 1024. Window [i0-48, i0+15].
// --------------------------------------------------------------------------
__global__ __launch_bounds__(128) void attn_tile(const unsigned short* __restrict__ Q,
                                                 const unsigned short* __restrict__ Kx,
                                                 const unsigned short* __restrict__ Vt,
                                                 float* __restrict__ out) {
  constexpr int PLD = 72;  // 64 + 8 pad shorts; row stride 144 B (16B-aligned)
  __shared__ unsigned short pls[16 * PLD];  // 2304 B
  __shared__ float lm[2][16], ls[2][16];

  const int t    = threadIdx.x;
  const int h    = t >> 6;
  const int lane = t & 63;
  const int q    = lane >> 4;
  const int c    = lane & 15;

  // XCD-contiguous swizzle: XCD x gets tiles [x*128, (x+1)*128)
  const int tile = ((blockIdx.x & 7) << 7) + (blockIdx.x >> 3);
  const int r0   = tile << 4;           // global query base
  const int b    = r0 >> 12;            // batch
  const int i0   = r0 & (SEQ - 1);      // local query base
  const int jb   = i0 - 48;             // window start (may be < 0)

#pragma unroll 1
  for (int rep = 0; rep < REPS_ATTN; ++rep) {
    asm volatile("" ::: "memory");

    // ---- Q fragments: 16 queries x 512 (both waves load the same Q) ----
    short8 qf[16];
    {
      const unsigned short* qp = Q + (size_t)(r0 + c) * D_MODEL + q * 8;
#pragma unroll
      for (int ch = 0; ch < 16; ++ch) qf[ch] = *(const short8*)(qp + ch * 32);
    }

    // ---- S = Q K^T for this wave's 2 subtiles (sj = 2h, 2h+1) ----
    float4v sacc[2];
    sacc[0] = (float4v){0.f, 0.f, 0.f, 0.f};
    sacc[1] = (float4v){0.f, 0.f, 0.f, 0.f};
#pragma unroll
    for (int s = 0; s < 2; ++s) {
      const int sj = 2 * h + s;
      if (jb + 16 * sj + 15 < 0) continue;
      int krow = jb + 16 * sj + c;
      if (krow < 0) krow = 0;
      const unsigned short* kr = Kx + ((size_t)(b << 12) + krow) * D_MODEL + q * 8;
      float4v sv = sacc[s];
#pragma unroll
      for (int ch = 0; ch < 16; ++ch)
        sv = __builtin_amdgcn_mfma_f32_16x16x32_bf16(qf[ch], *(const short8*)(kr + ch * 32), sv, 0, 0, 0);
      sacc[s] = sv;
    }

    // ---- prefetch V chunk 0 ----
    const unsigned short* vbase = Vt + (size_t)(h * 256 + c) * BS + (b << 12);
    const bool ch0 = (jb + 31 >= 0);
    short8 vf0[16];
    if (ch0) {
      int kk = jb + q * 8;
      if (kk < 0) kk = 0;
      const unsigned short* vb = vbase + kk;
#pragma unroll
      for (int dt = 0; dt < 16; ++dt) vf0[dt] = *(const short8*)(vb + (size_t)dt * 16 * BS);
    }

    // ---- ALiBi + causal/window mask + wave-local row max ----
    float tmax[4] = {-1e30f, -1e30f, -1e30f, -1e30f};
#pragma unroll
    for (int s = 0; s < 2; ++s)
#pragma unroll
      for (int tt = 0; tt < 4; ++tt) {
        const int jl = jb + 16 * (2 * h + s) + c;
        const int il = i0 + 4 * q + tt;
        float sv = sacc[s][tt];
        sv = (jl < 0 || jl > il) ? -1e30f : sv + 0.5f * (float)(jl - il);
        sacc[s][tt] = sv;
        tmax[tt] = fmaxf(tmax[tt], sv);
      }
#pragma unroll
    for (int tt = 0; tt < 4; ++tt) {
      float v = tmax[tt];
      v = fmaxf(v, __shfl_xor(v, 1, 64));
      v = fmaxf(v, __shfl_xor(v, 2, 64));
      v = fmaxf(v, __shfl_xor(v, 4, 64));
      v = fmaxf(v, __shfl_xor(v, 8, 64));
      tmax[tt] = v;
    }
    if (c == 0) {
#pragma unroll
      for (int tt = 0; tt < 4; ++tt) lm[h][4 * q + tt] = tmax[tt];
    }
    __syncthreads();

    // ---- global max, p = exp(s-m), P -> LDS, partial sums ----
    float m[4];
#pragma unroll
    for (int tt = 0; tt < 4; ++tt)
      m[tt] = fmaxf(lm[0][4 * q + tt], lm[1][4 * q + tt]);

    float rsum[4] = {0.f, 0.f, 0.f, 0.f};
#pragma unroll
    for (int s = 0; s < 2; ++s)
#pragma unroll
      for (int tt = 0; tt < 4; ++tt) {
        const float p = __expf(sacc[s][tt] - m[tt]);
        rsum[tt] += p;
        pls[(4 * q + tt) * PLD + (2 * h + s) * 16 + c] = bf16r(p);
      }
#pragma unroll
    for (int tt = 0; tt < 4; ++tt) {
      float v = rsum[tt];
      v += __shfl_xor(v, 1, 64);
      v += __shfl_xor(v, 2, 64);
      v += __shfl_xor(v, 4, 64);
      v += __shfl_xor(v, 8, 64);
      rsum[tt] = v;
    }
    if (c == 0) {
#pragma unroll
      for (int tt = 0; tt < 4; ++tt) ls[h][4 * q + tt] = rsum[tt];
    }
    __syncthreads();

    float l[4];
#pragma unroll
    for (int tt = 0; tt < 4; ++tt)
      l[tt] = ls[0][4 * q + tt] + ls[1][4 * q + tt];

    // ---- O = P V for D-half h, 64 keys ----
    float4v oacc[16];
#pragma unroll
    for (int dt = 0; dt < 16; ++dt) oacc[dt] = (float4v){0.f, 0.f, 0.f, 0.f};

    if (ch0) {
      const short8 pa = *(const short8*)&pls[c * PLD + q * 8];
#pragma unroll
      for (int dt = 0; dt < 16; ++dt)
        oacc[dt] = __builtin_amdgcn_mfma_f32_16x16x32_bf16(pa, vf0[dt], oacc[dt], 0, 0, 0);
    }
    {
      const short8 pa = *(const short8*)&pls[c * PLD + 32 + q * 8];
      int kk = jb + 32 + q * 8;
      if (kk < 0) kk = 0;
      const unsigned short* vb = vbase + kk;
#pragma unroll
      for (int dt = 0; dt < 16; ++dt) {
        const short8 vf = *(const short8*)(vb + (size_t)dt * 16 * BS);
        oacc[dt] = __builtin_amdgcn_mfma_f32_16x16x32_bf16(pa, vf, oacc[dt], 0, 0, 0);
      }
    }

    // ---- epilogue: O / l ----
    float inv[4];
#pragma unroll
    for (int tt = 0; tt < 4; ++tt) inv[tt] = 1.0f / l[tt];
#pragma unroll
    for (int dt = 0; dt < 16; ++dt)
#pragma unroll
      for (int tt = 0; tt < 4; ++tt)
        out[(size_t)(r0 + 4 * q + tt) * D_MODEL + h * 256 + dt * 16 + c] =
            oacc[dt][tt] * inv[tt];

    __syncthreads();  // rep-safety: pls reads done before next rep's writes
  }
}

// --------------------------------------------------------------------------
extern "C" void kernel_launch(void* const* d_in, const int* in_sizes, int n_in,
                              void* d_out, int out_size, void* d_ws,
                              size_t ws_size, hipStream_t stream) {
  const float* x   = (const float*)d_in[0];
  const float* Wqk = (const float*)d_in[1];
  const float* Wv  = (const float*)d_in[2];
  const float* bv  = (const float*)d_in[3];
  float* out = (float*)d_out;

  unsigned short* xb   = (unsigned short*)d_ws;                  // 16 MB
  unsigned short* Qb   = xb + (size_t)BS * D_MODEL;              // 16 MB
  unsigned short* Vt   = Qb + (size_t)BS * D_MODEL;              // 16 MB
  unsigned short* Wqkt = Vt + (size_t)BS * D_MODEL;              // 512 KB
  unsigned short* Wvb  = Wqkt + (size_t)D_MODEL * D_MODEL;       // 512 KB

  const float scale = 1.0f / sqrtf((float)D_MODEL);

  cvt_w<<<dim3(192), dim3(256), 0, stream>>>(Wqk, Wqkt, Wv, Wvb);
  qv_gemm<<<dim3(512), dim3(256), 0, stream>>>(x, Wqkt, Wvb, bv, xb, Qb, Vt, scale);
  attn_tile<<<dim3(BS / 16), dim3(128), 0, stream>>>(Qb, xb, Vt, out);
}

// Round 12
// 130.734 us; speedup vs baseline: 1.6213x; 1.6213x over previous
//
#include <hip/hip_runtime.h>
#include <math.h>

#define D_MODEL 512
#define SEQ     4096
#define BATCH   4
#define BS      (BATCH * SEQ)  // 16384

typedef __attribute__((ext_vector_type(8))) short  short8;   // 8 x bf16 (4 VGPRs)
typedef __attribute__((ext_vector_type(4))) float  float4v;  // MFMA C/D

#define GAS __attribute__((address_space(1)))
#define LAS __attribute__((address_space(3)))

__device__ __forceinline__ void gld_lds16(const void* g, void* l) {
  __builtin_amdgcn_global_load_lds((const GAS unsigned int*)g,
                                   (LAS unsigned int*)l, 16, 0, 0);
}

__device__ __forceinline__ unsigned short bf16r(float f) {
  unsigned int u = __builtin_bit_cast(unsigned int, f);
  u += 0x7fffu + ((u >> 16) & 1u);  // RTNE
  return (unsigned short)(u >> 16);
}

__device__ __forceinline__ uint4 pack8(float4 a, float4 b) {
  uint4 o;
  o.x = bf16r(a.x) | ((unsigned)bf16r(a.y) << 16);
  o.y = bf16r(a.z) | ((unsigned)bf16r(a.w) << 16);
  o.z = bf16r(b.x) | ((unsigned)bf16r(b.y) << 16);
  o.w = bf16r(b.z) | ((unsigned)bf16r(b.w) << 16);
  return o;
}

// --------------------------------------------------------------------------
// Weight prep only:
//   blocks 0..63  : W_qk [k][n] -> Wqkt [n][k] bf16 (tile transpose)
//   blocks 64..191: W_v straight convert to bf16
// --------------------------------------------------------------------------
__global__ __launch_bounds__(256) void cvt_w(const float* __restrict__ Wqk,
                                             unsigned short* __restrict__ Wqkt,
                                             const float* __restrict__ Wv,
                                             unsigned short* __restrict__ Wvb) {
  if (blockIdx.x < 64) {
    __shared__ float tile[64][65];
    const int bx = blockIdx.x & 7;   // n-tile
    const int by = blockIdx.x >> 3;  // k-tile
    const int tx = threadIdx.x & 63;
    const int ty = threadIdx.x >> 6;
    for (int r = ty; r < 64; r += 4)
      tile[r][tx] = Wqk[(size_t)(by * 64 + r) * D_MODEL + bx * 64 + tx];
    __syncthreads();
    for (int r = ty; r < 64; r += 4)
      Wqkt[(size_t)(bx * 64 + r) * D_MODEL + by * 64 + tx] = bf16r(tile[tx][r]);
  } else {
    const int idx = ((blockIdx.x - 64) * 256 + threadIdx.x) * 8;
    const float4 a = *(const float4*)(Wv + idx);
    const float4 b = *(const float4*)(Wv + idx + 4);
    *(uint4*)(Wvb + idx) = pack8(a, b);
  }
}

// --------------------------------------------------------------------------
// Fused convert + Q-GEMM + Vt-GEMM (round-10 version, unchanged).
// --------------------------------------------------------------------------
template <bool QP>
__device__ __forceinline__ void gemm_path(const float* __restrict__ x,
                                          const unsigned short* __restrict__ Wgt,
                                          const float* __restrict__ bias,
                                          unsigned short* __restrict__ xb,
                                          unsigned short* __restrict__ C,
                                          int a0, float scale,
                                          unsigned short* smem) {
  unsigned short* Ws = smem;          // 32768 shorts (64 KB)
  unsigned short* As = smem + 32768;  // 4096 shorts (8 KB)

  const int t    = threadIdx.x;
  const int w    = t >> 6;
  const int lane = t & 63;
  const int q    = lane >> 4;
  const int c    = lane & 15;
  const int wbase = w * 128;
  const int sw   = c & 7;

  const int arow = t >> 2;        // 0..63
  const int acb  = (t & 3) * 16;  // 0,16,32,48

  constexpr int NI = QP ? 8 : 4;
  constexpr int NJ = QP ? 4 : 8;

  float4v acc[NI][NJ];
#pragma unroll
  for (int i = 0; i < NI; ++i)
#pragma unroll
    for (int j = 0; j < NJ; ++j) acc[i][j] = (float4v){0.f, 0.f, 0.f, 0.f};

  for (int k0 = 0; k0 < D_MODEL; k0 += 64) {
#pragma unroll
    for (int it = 0; it < 16; ++it) {
      const int idx = it * 256 + t;  // 0..4095
      const int r   = idx >> 3;
      const int s   = idx & 7;
      gld_lds16(Wgt + (size_t)r * D_MODEL + k0 + ((s ^ (r & 7)) << 3),
                &Ws[idx * 8]);
    }
    {
      const float* xg = x + (size_t)(a0 + arow) * D_MODEL + k0 + acb;
      const float4 f0 = *(const float4*)(xg + 0);
      const float4 f1 = *(const float4*)(xg + 4);
      const float4 f2 = *(const float4*)(xg + 8);
      const float4 f3 = *(const float4*)(xg + 12);
      const uint4 u0 = pack8(f0, f1);
      const uint4 u1 = pack8(f2, f3);
      const int s0 = (t & 3) * 2;
      const int rk = arow & 7;
      *(uint4*)&As[arow * 64 + ((s0 ^ rk) << 3)]       = u0;
      *(uint4*)&As[arow * 64 + (((s0 + 1) ^ rk) << 3)] = u1;
      if (QP) {
        unsigned short* xo = xb + (size_t)(a0 + arow) * D_MODEL + k0 + acb;
        *(uint4*)xo       = u0;
        *(uint4*)(xo + 8) = u1;
      }
    }
    __syncthreads();

#pragma unroll
    for (int kc = 0; kc < 2; ++kc) {
      const int slot = ((kc * 4 + q) ^ sw) * 8;
      short8 af[NI], bf[NJ];
#pragma unroll
      for (int i = 0; i < NI; ++i) {
        const unsigned short* src = QP ? &Ws[(wbase + i * 16 + c) * 64 + slot]
                                       : &As[(i * 16 + c) * 64 + slot];
        af[i] = *(const short8*)src;
      }
#pragma unroll
      for (int j = 0; j < NJ; ++j) {
        const unsigned short* src = QP ? &As[(j * 16 + c) * 64 + slot]
                                       : &Ws[(wbase + j * 16 + c) * 64 + slot];
        bf[j] = *(const short8*)src;
      }
#pragma unroll
      for (int i = 0; i < NI; ++i)
#pragma unroll
        for (int j = 0; j < NJ; ++j)
          acc[i][j] = __builtin_amdgcn_mfma_f32_16x16x32_bf16(af[i], bf[j], acc[i][j], 0, 0, 0);
    }
    __syncthreads();
  }

  if (QP) {
    constexpr int LD = 520;
#pragma unroll
    for (int j = 0; j < NJ; ++j) {
      const int row = j * 16 + c;
#pragma unroll
      for (int i = 0; i < NI; ++i) {
        uint2 pkt;
        pkt.x = (unsigned)bf16r(scale * acc[i][j][0]) |
                ((unsigned)bf16r(scale * acc[i][j][1]) << 16);
        pkt.y = (unsigned)bf16r(scale * acc[i][j][2]) |
                ((unsigned)bf16r(scale * acc[i][j][3]) << 16);
        *(uint2*)&smem[row * LD + wbase + i * 16 + 4 * q] = pkt;
      }
    }
    __syncthreads();
#pragma unroll
    for (int it = 0; it < 16; ++it) {
      const int idx = it * 256 + t;
      const int row = idx >> 6;
      const int ch  = idx & 63;
      *(uint4*)&C[(size_t)(a0 + row) * D_MODEL + ch * 8] =
          *(const uint4*)&smem[row * LD + ch * 8];
    }
  } else {
    constexpr int LD = 72;
#pragma unroll
    for (int j = 0; j < NJ; ++j) {
      const int dim = wbase + j * 16 + c;
      const float bvv = bias[dim];
#pragma unroll
      for (int i = 0; i < NI; ++i) {
        uint2 pkt;
        pkt.x = (unsigned)bf16r(acc[i][j][0] + bvv) |
                ((unsigned)bf16r(acc[i][j][1] + bvv) << 16);
        pkt.y = (unsigned)bf16r(acc[i][j][2] + bvv) |
                ((unsigned)bf16r(acc[i][j][3] + bvv) << 16);
        *(uint2*)&smem[dim * LD + i * 16 + 4 * q] = pkt;
      }
    }
    __syncthreads();
#pragma unroll
    for (int it = 0; it < 16; ++it) {
      const int idx = it * 256 + t;
      const int dim = idx >> 3;
      const int ch  = idx & 7;
      *(uint4*)&C[(size_t)dim * BS + a0 + ch * 8] =
          *(const uint4*)&smem[dim * LD + ch * 8];
    }
  }
}

__global__ __launch_bounds__(256, 2) void qv_gemm(const float* __restrict__ x,
                                                  const unsigned short* __restrict__ Wqkt,
                                                  const unsigned short* __restrict__ Wvb,
                                                  const float* __restrict__ bv,
                                                  unsigned short* __restrict__ xb,
                                                  unsigned short* __restrict__ Qb,
                                                  unsigned short* __restrict__ Vt,
                                                  float scale) {
  __shared__ unsigned short smem[36864];  // 72 KB union
  if (blockIdx.x < 256)
    gemm_path<true>(x, Wqkt, nullptr, xb, Qb, blockIdx.x * 64, scale, smem);
  else
    gemm_path<false>(x, Wvb, bv, nullptr, Vt, (blockIdx.x - 256) * 64, 1.0f, smem);
}

// --------------------------------------------------------------------------
// Windowed causal ALiBi attention, 4-WAVE blocks (round-11 counters:
// MfmaUtil 2.9%, VALUBusy 6.6%, Occupancy 10% -> latency-bound at 8
// waves/CU with a long per-wave serial chain).
//   Block = 256 threads = 4 waves = one 16-query tile; grid = 1024
//   (-> 16 waves/CU resident, 2x round-11).
//   Wave h: S subtile sj=h (16 keys, 16 MFMA - half the old chain);
//   4-wave softmax exchange via LDS; PV for D-quarter h (128 dims,
//   8+8 MFMA - half the old chain).
//   Q staged in LDS ([16][520] pad -> 2-way banks = free): kills the
//   64-VGPR qf array (old VGPR=152 capped residency) and the 2x
//   redundant Q loads. V chunk-0 prefetch retained (8 frags).
// Window = keys [i0-48, i0+15]; excluded mass <= ~3e-8 at bf16 tol.
// --------------------------------------------------------------------------
__global__ __launch_bounds__(256) void attn_tile(const unsigned short* __restrict__ Q,
                                                 const unsigned short* __restrict__ Kx,
                                                 const unsigned short* __restrict__ Vt,
                                                 float* __restrict__ out) {
  constexpr int QLD = 520;  // 512 + 8 pad shorts -> 1040B row stride
  constexpr int PLD = 72;   // 64 + 8 pad shorts
  __shared__ unsigned short qls[16 * QLD];  // 16640 B
  __shared__ unsigned short pls[16 * PLD];  // 2304 B
  __shared__ float lm[4][16], ls[4][16];

  const int t    = threadIdx.x;
  const int h    = t >> 6;   // wave 0..3
  const int lane = t & 63;
  const int q    = lane >> 4;
  const int c    = lane & 15;

  // XCD-contiguous swizzle: XCD x gets tiles [x*128, (x+1)*128)
  const int tile = ((blockIdx.x & 7) << 7) + (blockIdx.x >> 3);
  const int r0   = tile << 4;           // global query base
  const int b    = r0 >> 12;            // batch
  const int i0   = r0 & (SEQ - 1);      // local query base
  const int jb   = i0 - 48;             // window start (may be < 0)

  // ---- stage Q tile into LDS: 16 rows x 512, coalesced 1KB row runs ----
#pragma unroll
  for (int i = 0; i < 4; ++i) {
    const int idx = i * 256 + t;      // 0..1023
    const int row = idx >> 6;
    const int ch  = idx & 63;
    *(uint4*)&qls[row * QLD + ch * 8] =
        *(const uint4*)&Q[(size_t)(r0 + row) * D_MODEL + ch * 8];
  }
  __syncthreads();

  // ---- S = Q K^T: wave h computes subtile sj = h (keys jb+16h..+15) ----
  float4v sacc = (float4v){0.f, 0.f, 0.f, 0.f};
  {
    const int sj = h;
    if (jb + 16 * sj + 15 >= 0) {
      int krow = jb + 16 * sj + c;
      if (krow < 0) krow = 0;  // masked below
      const unsigned short* kr = Kx + ((size_t)(b << 12) + krow) * D_MODEL + q * 8;
#pragma unroll
      for (int ch = 0; ch < 16; ++ch) {
        const short8 qf = *(const short8*)&qls[c * QLD + ch * 32 + q * 8];
        sacc = __builtin_amdgcn_mfma_f32_16x16x32_bf16(qf, *(const short8*)(kr + ch * 32), sacc, 0, 0, 0);
      }
    }
  }

  // ---- prefetch V chunk 0 for D-quarter h (latency hides under softmax) ----
  const unsigned short* vbase = Vt + (size_t)(h * 128 + c) * BS + (b << 12);
  const bool ch0 = (jb + 31 >= 0);
  short8 vf0[8];
  if (ch0) {
    int kk = jb + q * 8;
    if (kk < 0) kk = 0;  // p == 0 there
    const unsigned short* vb = vbase + kk;
#pragma unroll
    for (int dt = 0; dt < 8; ++dt) vf0[dt] = *(const short8*)(vb + (size_t)dt * 16 * BS);
  }

  // ---- ALiBi + causal/window mask + wave-local row max (16 keys) ----
  float tmax[4];
#pragma unroll
  for (int tt = 0; tt < 4; ++tt) {
    const int jl = jb + 16 * h + c;
    const int il = i0 + 4 * q + tt;
    float sv = sacc[tt];
    sv = (jl < 0 || jl > il) ? -1e30f : sv + 0.5f * (float)(jl - il);
    sacc[tt] = sv;
    float v = sv;
    v = fmaxf(v, __shfl_xor(v, 1, 64));
    v = fmaxf(v, __shfl_xor(v, 2, 64));
    v = fmaxf(v, __shfl_xor(v, 4, 64));
    v = fmaxf(v, __shfl_xor(v, 8, 64));
    tmax[tt] = v;
  }
  if (c == 0) {
#pragma unroll
    for (int tt = 0; tt < 4; ++tt) lm[h][4 * q + tt] = tmax[tt];
  }
  __syncthreads();  // 4-wave barrier (also drains vf0 prefetch)

  // ---- global max, p = exp(s-m), P -> LDS, partial sums ----
  float rsum[4];
#pragma unroll
  for (int tt = 0; tt < 4; ++tt) {
    const float m = fmaxf(fmaxf(lm[0][4 * q + tt], lm[1][4 * q + tt]),
                          fmaxf(lm[2][4 * q + tt], lm[3][4 * q + tt]));
    const float p = __expf(sacc[tt] - m);
    pls[(4 * q + tt) * PLD + h * 16 + c] = bf16r(p);
    float v = p;
    v += __shfl_xor(v, 1, 64);
    v += __shfl_xor(v, 2, 64);
    v += __shfl_xor(v, 4, 64);
    v += __shfl_xor(v, 8, 64);
    rsum[tt] = v;
  }
  if (c == 0) {
#pragma unroll
    for (int tt = 0; tt < 4; ++tt) ls[h][4 * q + tt] = rsum[tt];
  }
  __syncthreads();  // 4-wave barrier

  float l[4];
#pragma unroll
  for (int tt = 0; tt < 4; ++tt)
    l[tt] = ls[0][4 * q + tt] + ls[1][4 * q + tt] +
            ls[2][4 * q + tt] + ls[3][4 * q + tt];

  // ---- O = P V for D-quarter h (dims h*128 .. +127), 64 keys ----
  float4v oacc[8];
#pragma unroll
  for (int dt = 0; dt < 8; ++dt) oacc[dt] = (float4v){0.f, 0.f, 0.f, 0.f};

  // chunk 0: V already resident in vf0
  if (ch0) {
    const short8 pa = *(const short8*)&pls[c * PLD + q * 8];
#pragma unroll
    for (int dt = 0; dt < 8; ++dt)
      oacc[dt] = __builtin_amdgcn_mfma_f32_16x16x32_bf16(pa, vf0[dt], oacc[dt], 0, 0, 0);
  }
  // chunk 1: loads overlap chunk-0 MFMAs (no barrier between)
  {
    const short8 pa = *(const short8*)&pls[c * PLD + 32 + q * 8];
    int kk = jb + 32 + q * 8;
    if (kk < 0) kk = 0;  // p == 0 there
    const unsigned short* vb = vbase + kk;
#pragma unroll
    for (int dt = 0; dt < 8; ++dt) {
      const short8 vf = *(const short8*)(vb + (size_t)dt * 16 * BS);
      oacc[dt] = __builtin_amdgcn_mfma_f32_16x16x32_bf16(pa, vf, oacc[dt], 0, 0, 0);
    }
  }

  // ---- epilogue: O / l ----
  float inv[4];
#pragma unroll
  for (int tt = 0; tt < 4; ++tt) inv[tt] = 1.0f / l[tt];
#pragma unroll
  for (int dt = 0; dt < 8; ++dt)
#pragma unroll
    for (int tt = 0; tt < 4; ++tt)
      out[(size_t)(r0 + 4 * q + tt) * D_MODEL + h * 128 + dt * 16 + c] =
          oacc[dt][tt] * inv[tt];
}

// --------------------------------------------------------------------------
extern "C" void kernel_launch(void* const* d_in, const int* in_sizes, int n_in,
                              void* d_out, int out_size, void* d_ws,
                              size_t ws_size, hipStream_t stream) {
  const float* x   = (const float*)d_in[0];
  const float* Wqk = (const float*)d_in[1];
  const float* Wv  = (const float*)d_in[2];
  const float* bv  = (const float*)d_in[3];
  float* out = (float*)d_out;

  unsigned short* xb   = (unsigned short*)d_ws;                  // 16 MB
  unsigned short* Qb   = xb + (size_t)BS * D_MODEL;              // 16 MB
  unsigned short* Vt   = Qb + (size_t)BS * D_MODEL;              // 16 MB
  unsigned short* Wqkt = Vt + (size_t)BS * D_MODEL;              // 512 KB
  unsigned short* Wvb  = Wqkt + (size_t)D_MODEL * D_MODEL;       // 512 KB

  const float scale = 1.0f / sqrtf((float)D_MODEL);

  cvt_w<<<dim3(192), dim3(256), 0, stream>>>(Wqk, Wqkt, Wv, Wvb);
  qv_gemm<<<dim3(512), dim3(256), 0, stream>>>(x, Wqkt, Wvb, bv, xb, Qb, Vt, scale);
  attn_tile<<<dim3(BS / 16), dim3(256), 0, stream>>>(Qb, xb, Vt, out);
}